// Round 4
// baseline (152.261 us; speedup 1.0000x reference)
//
#include <hip/hip_runtime.h>
#include <hip/hip_bf16.h>
#include <hip/hip_cooperative_groups.h>

namespace cg = cooperative_groups;

// Problem constants (SparseEmbeddingHead): B=32, S=512, H=1024, V=250002
#define BB 32
#define SS 512
#define HH 1024
#define VV 250002
#define TOKENS (BB * SS)          // 16384
#define OUT_FLOATS (BB * VV)      // 8000064 (divisible by 4)
#define OUT_F4 (OUT_FLOATS / 4)   // 2000016

#define NB 1024
#define NT 256
#define WAVES (NB * NT / 64)      // 4096
#define TPW (TOKENS / WAVES)      // 4 tokens per wave

typedef float floatx4 __attribute__((ext_vector_type(4)));

// Fused cooperative kernel: per-wave token dots + grid-stride zero of out,
// grid sync, then each wave scatter-adds its own token weights from regs.
__global__ __launch_bounds__(NT) void fused_coop(
    const float* __restrict__ hidden,   // [TOKENS, H]
    const int* __restrict__ ids,        // [TOKENS]
    const float* __restrict__ mask,     // [TOKENS]
    const float* __restrict__ W,        // [H]
    const float* __restrict__ bias,     // [1]
    float* __restrict__ out)            // [B*V]
{
    const int tid = blockIdx.x * NT + threadIdx.x;
    const int lane = threadIdx.x & 63;
    const int wave = tid >> 6;          // 0..WAVES-1

    const float4* __restrict__ w4 = reinterpret_cast<const float4*>(W);
    const float bias0 = bias[0];

    float tw[TPW];
#pragma unroll
    for (int tt = 0; tt < TPW; ++tt) {
        const int token = wave * TPW + tt;
        const float4* __restrict__ h4 =
            reinterpret_cast<const float4*>(hidden + (size_t)token * HH);
        float sum = 0.0f;
#pragma unroll
        for (int i = 0; i < 4; ++i) {
            const float4 hv = h4[i * 64 + lane];
            const float4 wv = w4[i * 64 + lane];
            sum = fmaf(hv.x, wv.x, sum);
            sum = fmaf(hv.y, wv.y, sum);
            sum = fmaf(hv.z, wv.z, sum);
            sum = fmaf(hv.w, wv.w, sum);
        }
#pragma unroll
        for (int off = 32; off > 0; off >>= 1)
            sum += __shfl_xor(sum, off, 64);
        tw[tt] = fmaxf((sum + bias0) * mask[token], 0.0f);
    }

    // Zero the output (grid-stride, nontemporal streaming stores).
    floatx4* __restrict__ o4 = reinterpret_cast<floatx4*>(out);
    const floatx4 z = {0.f, 0.f, 0.f, 0.f};
    for (int i = tid; i < OUT_F4; i += NB * NT)
        __builtin_nontemporal_store(z, &o4[i]);

    cg::this_grid().sync();

    // Scatter from registers (lane 0 of each wave holds the reduced sums).
    if (lane == 0) {
#pragma unroll
        for (int tt = 0; tt < TPW; ++tt) {
            if (tw[tt] != 0.0f) {
                const int token = wave * TPW + tt;
                atomicAdd(&out[(size_t)(token / SS) * VV + ids[token]], tw[tt]);
            }
        }
    }
}

// ---- fallback path (non-cooperative), same as round-3 proven kernel ----
__global__ __launch_bounds__(256) void k1_zero_and_dot(
    const float* __restrict__ hidden, const float* __restrict__ mask,
    const float* __restrict__ W, const float* __restrict__ bias,
    float* __restrict__ out, float* __restrict__ tw_ws)
{
    const int tid = blockIdx.x * 256 + threadIdx.x;
    const int lane = threadIdx.x & 63;
    const int wave_global = tid >> 6;
    const float4* __restrict__ w4 = reinterpret_cast<const float4*>(W);
    const float bias0 = bias[0];
#pragma unroll
    for (int tt = 0; tt < 2; ++tt) {
        const int token = wave_global * 2 + tt;
        const float4* __restrict__ h4 =
            reinterpret_cast<const float4*>(hidden + (size_t)token * HH);
        float sum = 0.0f;
#pragma unroll
        for (int i = 0; i < 4; ++i) {
            const float4 hv = h4[i * 64 + lane];
            const float4 wv = w4[i * 64 + lane];
            sum = fmaf(hv.x, wv.x, sum);
            sum = fmaf(hv.y, wv.y, sum);
            sum = fmaf(hv.z, wv.z, sum);
            sum = fmaf(hv.w, wv.w, sum);
        }
#pragma unroll
        for (int off = 32; off > 0; off >>= 1)
            sum += __shfl_xor(sum, off, 64);
        if (lane == 0)
            tw_ws[token] = fmaxf((sum + bias0) * mask[token], 0.0f);
    }
    floatx4* __restrict__ o4 = reinterpret_cast<floatx4*>(out);
    const floatx4 z = {0.f, 0.f, 0.f, 0.f};
    for (int i = tid; i < OUT_F4; i += 2048 * 256)
        __builtin_nontemporal_store(z, &o4[i]);
}

__global__ __launch_bounds__(256) void k2_scatter(
    const float* __restrict__ tw_ws, const int* __restrict__ ids,
    float* __restrict__ out)
{
    const int t = blockIdx.x * 256 + threadIdx.x;
    if (t >= TOKENS) return;
    const float tw = tw_ws[t];
    if (tw != 0.0f)
        atomicAdd(&out[(size_t)(t / SS) * VV + ids[t]], tw);
}

extern "C" void kernel_launch(void* const* d_in, const int* in_sizes, int n_in,
                              void* d_out, int out_size, void* d_ws, size_t ws_size,
                              hipStream_t stream) {
    const float* hidden = (const float*)d_in[0];
    const int*   ids    = (const int*)d_in[1];
    const float* mask   = (const float*)d_in[2];
    const float* W      = (const float*)d_in[3];
    const float* bias   = (const float*)d_in[4];
    float* out   = (float*)d_out;
    float* tw_ws = (float*)d_ws;

    void* args[] = {(void*)&hidden, (void*)&ids, (void*)&mask,
                    (void*)&W, (void*)&bias, (void*)&out};
    hipError_t err = hipLaunchCooperativeKernel(
        reinterpret_cast<void*>(fused_coop), dim3(NB), dim3(NT), args, 0, stream);
    if (err != hipSuccess) {
        // Fallback: proven two-kernel path.
        k1_zero_and_dot<<<2048, 256, 0, stream>>>(hidden, mask, W, bias, out, tw_ws);
        k2_scatter<<<(TOKENS + 255) / 256, 256, 0, stream>>>(tw_ws, ids, out);
    }
}

// Round 5
// 23.607 us; speedup vs baseline: 6.4499x; 6.4499x over previous
//
#include <hip/hip_runtime.h>
#include <hip/hip_bf16.h>

// Problem constants (SparseEmbeddingHead): B=32, S=512, H=1024, V=250002
#define BB 32
#define SS 512
#define HH 1024
#define VV 250002
#define TOKENS (BB * SS)          // 16384
#define OUT_FLOATS (BB * VV)      // 8000064 (divisible by 4)
#define OUT_F4 (OUT_FLOATS / 4)   // 2000016

typedef float floatx4 __attribute__((ext_vector_type(4)));

// K1: pure streaming zero of the [B,V] output. Write-only -> full write BW.
#define Z_BLOCKS 2048
#define Z_THREADS 256
__global__ __launch_bounds__(Z_THREADS) void k1_zero(float* __restrict__ out)
{
    const int tid = blockIdx.x * Z_THREADS + threadIdx.x;
    floatx4* __restrict__ o4 = reinterpret_cast<floatx4*>(out);
    const floatx4 z = {0.f, 0.f, 0.f, 0.f};
    for (int i = tid; i < OUT_F4; i += Z_BLOCKS * Z_THREADS)
        __builtin_nontemporal_store(z, &o4[i]);
}

// K2: fused dot + scatter. One wave per 2 tokens; lane reads 4 float4 per
// token (coalesced 16B/lane), butterfly-reduce, lane 0 atomics into out.
// Read-dominated: 67 MB hidden (partially L3-resident across replays).
#define D_BLOCKS 2048
#define D_THREADS 256
__global__ __launch_bounds__(D_THREADS) void k2_dot_scatter(
    const float* __restrict__ hidden,   // [TOKENS, H]
    const int* __restrict__ ids,        // [TOKENS]
    const float* __restrict__ mask,     // [TOKENS]
    const float* __restrict__ W,        // [H]
    const float* __restrict__ bias,     // [1]
    float* __restrict__ out)            // [B*V] (zeroed by K1)
{
    const int tid = blockIdx.x * D_THREADS + threadIdx.x;
    const int lane = threadIdx.x & 63;
    const int wave = tid >> 6;          // 0..8191

    const float4* __restrict__ w4 = reinterpret_cast<const float4*>(W);
    const float bias0 = bias[0];

    // Load both tokens' data up-front for ILP (8 outstanding 16B loads).
    const float4* __restrict__ h4a =
        reinterpret_cast<const float4*>(hidden + (size_t)(wave * 2 + 0) * HH);
    const float4* __restrict__ h4b =
        reinterpret_cast<const float4*>(hidden + (size_t)(wave * 2 + 1) * HH);

    float4 ha[4], hb[4], wv[4];
#pragma unroll
    for (int i = 0; i < 4; ++i) ha[i] = h4a[i * 64 + lane];
#pragma unroll
    for (int i = 0; i < 4; ++i) hb[i] = h4b[i * 64 + lane];
#pragma unroll
    for (int i = 0; i < 4; ++i) wv[i] = w4[i * 64 + lane];

    float sa = 0.f, sb = 0.f;
#pragma unroll
    for (int i = 0; i < 4; ++i) {
        sa = fmaf(ha[i].x, wv[i].x, sa); sa = fmaf(ha[i].y, wv[i].y, sa);
        sa = fmaf(ha[i].z, wv[i].z, sa); sa = fmaf(ha[i].w, wv[i].w, sa);
        sb = fmaf(hb[i].x, wv[i].x, sb); sb = fmaf(hb[i].y, wv[i].y, sb);
        sb = fmaf(hb[i].z, wv[i].z, sb); sb = fmaf(hb[i].w, wv[i].w, sb);
    }

#pragma unroll
    for (int off = 32; off > 0; off >>= 1) {
        sa += __shfl_xor(sa, off, 64);
        sb += __shfl_xor(sb, off, 64);
    }

    if (lane == 0) {
        const int t0 = wave * 2;
        const float twa = fmaxf((sa + bias0) * mask[t0], 0.0f);
        const float twb = fmaxf((sb + bias0) * mask[t0 + 1], 0.0f);
        if (twa != 0.0f)
            atomicAdd(&out[(size_t)(t0 / SS) * VV + ids[t0]], twa);
        if (twb != 0.0f)
            atomicAdd(&out[(size_t)((t0 + 1) / SS) * VV + ids[t0 + 1]], twb);
    }
}

extern "C" void kernel_launch(void* const* d_in, const int* in_sizes, int n_in,
                              void* d_out, int out_size, void* d_ws, size_t ws_size,
                              hipStream_t stream) {
    const float* hidden = (const float*)d_in[0];
    const int*   ids    = (const int*)d_in[1];
    const float* mask   = (const float*)d_in[2];
    const float* W      = (const float*)d_in[3];
    const float* bias   = (const float*)d_in[4];
    float* out = (float*)d_out;

    k1_zero<<<Z_BLOCKS, Z_THREADS, 0, stream>>>(out);
    k2_dot_scatter<<<D_BLOCKS, D_THREADS, 0, stream>>>(hidden, ids, mask, W, bias, out);
}